// Round 15
// baseline (283.048 us; speedup 1.0000x reference)
//
#include <hip/hip_runtime.h>

#define N_NODES   8192
#define N_EDGES   65536
#define IN_DIM    768
#define HIDDEN    4096
#define N_CLASSES 16
#define SLOTS     64

typedef unsigned short ushort_t;
typedef __attribute__((ext_vector_type(8))) short bf16x8;
typedef __attribute__((ext_vector_type(4))) float f32x4;

__device__ __forceinline__ ushort_t f2bf(float f) {
    union { float f; unsigned i; } v; v.f = f;
    unsigned r = v.i + 0x7FFFu + ((v.i >> 16) & 1u);   // RNE
    return (ushort_t)(r >> 16);
}
__device__ __forceinline__ float bf2f(ushort_t u) {
    union { unsigned i; float f; } v; v.i = ((unsigned)u) << 16; return v.f;
}

// offset field intentionally NOT used: semantics unverified on gfx950 (round-10 NaN)
#define GLD_LDS16(gp, lp) \
    __builtin_amdgcn_global_load_lds((const __attribute__((address_space(1))) void*)(gp), \
                                     (__attribute__((address_space(3))) void*)(lp), 16, 0, 0)

__device__ __forceinline__ int esrc(const int* ei, int f32mode, int e) {
    return f32mode ? ei[e] : ei[2 * e];
}
__device__ __forceinline__ int edst(const int* ei, int f32mode, int e) {
    return f32mode ? ei[N_EDGES + e] : ei[2 * N_EDGES + 2 * e];
}

// ---------------- phase1: conv_w2 + conv_x + bucket ----------------
// b [0,16):       W2 fp32 [4096][16] -> W2T bf16 [16][4096]
// b [16,1552):    x fp32 -> xbf bf16
// b [1552,1808):  edge-layout detect + fixed-stride bucketing
__global__ __launch_bounds__(256) void phase1(const float* __restrict__ x,
                                              ushort_t* __restrict__ xbf,
                                              const float* __restrict__ W2,
                                              ushort_t* __restrict__ W2T,
                                              const int* __restrict__ ei,
                                              int* __restrict__ cnt,
                                              int* __restrict__ slots,
                                              int* __restrict__ flag) {
    int b = blockIdx.x, t = threadIdx.x;
    if (b < 16) {
        __shared__ ushort_t ld[16 * 257];
        int k0 = b * 256;
        const float4* src = (const float4*)(W2 + (long)(k0 + t) * N_CLASSES);
        #pragma unroll
        for (int j = 0; j < 4; j++) {
            float4 v = src[j];
            ld[(j * 4 + 0) * 257 + t] = f2bf(v.x);
            ld[(j * 4 + 1) * 257 + t] = f2bf(v.y);
            ld[(j * 4 + 2) * 257 + t] = f2bf(v.z);
            ld[(j * 4 + 3) * 257 + t] = f2bf(v.w);
        }
        __syncthreads();
        #pragma unroll
        for (int c = 0; c < 16; c++)
            W2T[c * HIDDEN + k0 + t] = ld[c * 257 + t];
    } else if (b < 1552) {
        long i = (long)(b - 16) * 1024 + t;            // 1536 blocks x 4 float4/thread
        #pragma unroll
        for (int p = 0; p < 4; p++) {
            float4 v = ((const float4*)x)[i + p * 256];
            ushort4 r = { f2bf(v.x), f2bf(v.y), f2bf(v.z), f2bf(v.w) };
            ((ushort4*)xbf)[i + p * 256] = r;
        }
    } else {
        // per-block layout detect: int32 layout -> odd words are real values (nonzero
        // over 4096 samples); int64 layout -> odd words are high halves == 0.
        __shared__ int sv[256];
        int v = 0;
        for (int e = t; e < 4096; e += 256) v |= ei[2 * e + 1];
        sv[t] = v;
        __syncthreads();
        for (int off = 128; off > 0; off >>= 1) {
            if (t < off) sv[t] |= sv[t + off];
            __syncthreads();
        }
        int f = (sv[0] != 0) ? 1 : 0;
        if (b == 1552 && t == 0) *flag = f;            // for aggregate's overflow path
        int e = (b - 1552) * 256 + t;                  // 65536
        int s = esrc(ei, f, e), d = edst(ei, f, e);
        int p = atomicAdd(&cnt[d], 1);
        if (p < SLOTS) slots[d * SLOTS + p] = s;
    }
}

// ---------------- phase2: conv_w1 + aggregate ----------------
// b [0,3072):      W1 fp32 [768][4096] -> W1T bf16 [4096][768]
// b [3072,11264):  aggregate node b-3072 (threads 0..191; wave 3 retires)
__global__ __launch_bounds__(256) void phase2(const float* __restrict__ W1,
                                              ushort_t* __restrict__ W1T,
                                              const ushort_t* __restrict__ xbf,
                                              const int* __restrict__ cnt,
                                              const int* __restrict__ slots,
                                              const int* __restrict__ ei,
                                              const int* __restrict__ flag,
                                              ushort_t* __restrict__ xagg) {
    int b = blockIdx.x, t = threadIdx.x;
    if (b < 3072) {
        __shared__ ushort_t tile[32][33];
        int n0 = (b & 127) * 32, k0 = (b >> 7) * 32;
        int tx = t & 31, ty = t >> 5;                  // ty: 0..7
        #pragma unroll
        for (int j = 0; j < 4; j++) {
            int k = ty * 4 + j;
            tile[k][tx] = f2bf(W1[(k0 + k) * HIDDEN + n0 + tx]);
        }
        __syncthreads();
        #pragma unroll
        for (int j = 0; j < 4; j++) {
            int n = ty * 4 + j;
            W1T[(n0 + n) * IN_DIM + k0 + tx] = tile[tx][n];
        }
        return;
    }
    if (t >= 192) return;                              // wave 3 idle in aggregate blocks
    int w = t >> 6, l = t & 63;
    int d = b - 3072;
    int fo = w * 256 + l * 4;                          // feature offset
    int cd = cnt[d];
    float wd = rsqrtf((float)(cd + 1));
    ushort4 sv = *(const ushort4*)(xbf + (long)d * IN_DIM + fo);
    float a0 = wd * bf2f(sv.x), a1 = wd * bf2f(sv.y);
    float a2 = wd * bf2f(sv.z), a3 = wd * bf2f(sv.w);

    if (cd <= SLOTS) {
        const int* sl = slots + d * SLOTS;
        int j = 0;
        for (; j + 4 <= cd; j += 4) {
            int s0 = sl[j], s1 = sl[j + 1], s2 = sl[j + 2], s3 = sl[j + 3];
            float w0 = rsqrtf((float)(cnt[s0] + 1));
            float w1 = rsqrtf((float)(cnt[s1] + 1));
            float w2 = rsqrtf((float)(cnt[s2] + 1));
            float w3 = rsqrtf((float)(cnt[s3] + 1));
            ushort4 v0 = *(const ushort4*)(xbf + (long)s0 * IN_DIM + fo);
            ushort4 v1 = *(const ushort4*)(xbf + (long)s1 * IN_DIM + fo);
            ushort4 v2 = *(const ushort4*)(xbf + (long)s2 * IN_DIM + fo);
            ushort4 v3 = *(const ushort4*)(xbf + (long)s3 * IN_DIM + fo);
            a0 = fmaf(w0, bf2f(v0.x), a0); a1 = fmaf(w0, bf2f(v0.y), a1);
            a2 = fmaf(w0, bf2f(v0.z), a2); a3 = fmaf(w0, bf2f(v0.w), a3);
            a0 = fmaf(w1, bf2f(v1.x), a0); a1 = fmaf(w1, bf2f(v1.y), a1);
            a2 = fmaf(w1, bf2f(v1.z), a2); a3 = fmaf(w1, bf2f(v1.w), a3);
            a0 = fmaf(w2, bf2f(v2.x), a0); a1 = fmaf(w2, bf2f(v2.y), a1);
            a2 = fmaf(w2, bf2f(v2.z), a2); a3 = fmaf(w2, bf2f(v2.w), a3);
            a0 = fmaf(w3, bf2f(v3.x), a0); a1 = fmaf(w3, bf2f(v3.y), a1);
            a2 = fmaf(w3, bf2f(v3.z), a2); a3 = fmaf(w3, bf2f(v3.w), a3);
        }
        for (; j < cd; j++) {
            int s = sl[j];
            float ws = rsqrtf((float)(cnt[s] + 1));
            ushort4 v = *(const ushort4*)(xbf + (long)s * IN_DIM + fo);
            a0 = fmaf(ws, bf2f(v.x), a0); a1 = fmaf(ws, bf2f(v.y), a1);
            a2 = fmaf(ws, bf2f(v.z), a2); a3 = fmaf(ws, bf2f(v.w), a3);
        }
    } else {
        int f = *flag;
        for (int e = 0; e < N_EDGES; e++) {
            if (edst(ei, f, e) == d) {
                int s = esrc(ei, f, e);
                float ws = rsqrtf((float)(cnt[s] + 1));
                ushort4 v = *(const ushort4*)(xbf + (long)s * IN_DIM + fo);
                a0 = fmaf(ws, bf2f(v.x), a0); a1 = fmaf(ws, bf2f(v.y), a1);
                a2 = fmaf(ws, bf2f(v.z), a2); a3 = fmaf(ws, bf2f(v.w), a3);
            }
        }
    }
    ushort4 r = { f2bf(a0 * wd), f2bf(a1 * wd), f2bf(a2 * wd), f2bf(a3 * wd) };
    *(ushort4*)(xagg + (long)d * IN_DIM + fo) = r;
}

// ---------------- fused GEMM1 + ReLU + partial GEMM2 (32 slabs) ----------------
// BK=64, persistent staging pointers (R14). Two-pass epilogue shrinks LDS to 32768
// -> 5 blocks/CU (was 4 at 40960). XOR bank swizzle on staging.
__global__ __launch_bounds__(256, 5) void gemm1_fused(const ushort_t* __restrict__ A,
                                                      const ushort_t* __restrict__ Bt,
                                                      const float* __restrict__ b1,
                                                      const ushort_t* __restrict__ W2T,
                                                      float* __restrict__ part) {
    __shared__ char smem[32768];
    ushort_t* ldsA = (ushort_t*)smem;              // [2][128*32] bf16 = 16 KB
    ushort_t* ldsB = (ushort_t*)(smem + 16384);    // [2][128*32] bf16 = 16 KB
    int bx = blockIdx.x & 31;          // n tile  (4096/128 = 32)
    int by = blockIdx.x >> 5;          // m tile  (8192/128 = 64)
    int m0 = by * 128, n0 = bx * 128;
    int t = threadIdx.x;
    int w = t >> 6, l = t & 63;
    int wm = w & 1, wn = w >> 1;
    int q = l >> 4, lm = l & 15;

    f32x4 acc[4][4] = {};

    // swizzled fragment-read offsets (constant across K since single-buffered)
    int offA[4], offB[4];
    #pragma unroll
    for (int mt = 0; mt < 4; mt++) {
        int m = wm * 64 + mt * 16 + lm;
        offA[mt] = m * 32 + (q ^ ((m >> 1) & 3)) * 8;
    }
    #pragma unroll
    for (int nt = 0; nt < 4; nt++) {
        int n = wn * 64 + nt * 16 + lm;
        offB[nt] = n * 32 + (q ^ ((n >> 1) & 3)) * 8;
    }

    // persistent staging pointers: [slab][i] for A and B, bumped each iteration
    const ushort_t* pA[2][2];
    const ushort_t* pB[2][2];
    #pragma unroll
    for (int i = 0; i < 2; i++) {
        int L = i * 256 + t;
        int row = L >> 2;
        int cg = (L & 3) ^ ((row >> 1) & 3);
        const ushort_t* a0 = A + (long)(m0 + row) * IN_DIM + cg * 8;
        const ushort_t* b0 = Bt + (long)(n0 + row) * IN_DIM + cg * 8;
        pA[0][i] = a0;      pA[1][i] = a0 + 32;
        pB[0][i] = b0;      pB[1][i] = b0 + 32;
    }

    for (int it = 0; it < IN_DIM / 64; it++) {     // 12 iterations
        __syncthreads();
        #pragma unroll
        for (int i = 0; i < 2; i++) {
            GLD_LDS16(pA[0][i], ldsA + (i * 256 + w * 64) * 8);
            GLD_LDS16(pB[0][i], ldsB + (i * 256 + w * 64) * 8);
            GLD_LDS16(pA[1][i], ldsA + 4096 + (i * 256 + w * 64) * 8);
            GLD_LDS16(pB[1][i], ldsB + 4096 + (i * 256 + w * 64) * 8);
        }
        #pragma unroll
        for (int i = 0; i < 2; i++) {              // bump: +64 k-positions
            pA[0][i] += 64; pA[1][i] += 64;
            pB[0][i] += 64; pB[1][i] += 64;
        }
        __syncthreads();

        #pragma unroll
        for (int j = 0; j < 2; j++) {
            bf16x8 af[4], bfr[4];
            #pragma unroll
            for (int mt = 0; mt < 4; mt++)
                af[mt] = *(const bf16x8*)(ldsA + j * 4096 + offA[mt]);
            #pragma unroll
            for (int nt = 0; nt < 4; nt++)
                bfr[nt] = *(const bf16x8*)(ldsB + j * 4096 + offB[nt]);
            #pragma unroll
            for (int mt = 0; mt < 4; mt++)
                #pragma unroll
                for (int nt = 0; nt < 4; nt++)
                    acc[mt][nt] = __builtin_amdgcn_mfma_f32_16x16x32_bf16(af[mt], bfr[nt], acc[mt][nt], 0, 0, 0);
        }
    }

    // ---- two-pass epilogue: bias+ReLU, C->A layout via 32-row LDS slab, x W2T ----
    __syncthreads();   // all waves done reading staging LDS before overwrite
    const int RP = 80;                                   // padded row (16B-aligned stride)
    ushort_t* myhl = (ushort_t*)smem + w * 32 * RP;      // per-wave 32x80 bf16 = 5 KB

    float bias[4];
    #pragma unroll
    for (int nt = 0; nt < 4; nt++) bias[nt] = b1[n0 + wn * 64 + nt * 16 + lm];

    bf16x8 bf2[2];
    #pragma unroll
    for (int kk = 0; kk < 2; kk++)
        bf2[kk] = *(const bf16x8*)(W2T + (long)lm * HIDDEN + n0 + wn * 64 + kk * 32 + q * 8);

    f32x4 acc2[4] = {};
    #pragma unroll
    for (int h = 0; h < 2; h++) {                        // mt halves {0,1}, {2,3}
        #pragma unroll
        for (int mt2 = 0; mt2 < 2; mt2++) {
            int mt = h * 2 + mt2;
            #pragma unroll
            for (int nt = 0; nt < 4; nt++) {
                #pragma unroll
                for (int r = 0; r < 4; r++) {
                    float v = acc[mt][nt][r] + bias[nt];
                    v = v > 0.0f ? v : 0.0f;
                    // C layout: local row = mt2*16 + q*4 + r, col = nt*16 + lm
                    myhl[(mt2 * 16 + q * 4 + r) * RP + nt * 16 + lm] = f2bf(v);
                }
            }
        }
        // same-wave DS ops to aliasing addresses stay ordered; no barrier needed
        #pragma unroll
        for (int kk = 0; kk < 2; kk++)
            #pragma unroll
            for (int mt2 = 0; mt2 < 2; mt2++) {
                bf16x8 a2 = *(const bf16x8*)(myhl + (mt2 * 16 + lm) * RP + kk * 32 + q * 8);
                acc2[h * 2 + mt2] = __builtin_amdgcn_mfma_f32_16x16x32_bf16(a2, bf2[kk], acc2[h * 2 + mt2], 0, 0, 0);
            }
    }

    // ---- merge wn=0/wn=1 partials through LDS (17-padded, conflict-free) ----
    float* psum = (float*)smem;                          // [2][64][17] fp32 = 8.7 KB
    __syncthreads();                                     // all myhl reads done
    if (wn == 1) {
        #pragma unroll
        for (int mt = 0; mt < 4; mt++)
            #pragma unroll
            for (int r = 0; r < 4; r++)
                psum[(wm * 64 + mt * 16 + q * 4 + r) * 17 + lm] = acc2[mt][r];
    }
    __syncthreads();
    if (wn == 0) {
        float* pslab = part + ((long)bx * N_NODES + m0 + wm * 64) * N_CLASSES;
        #pragma unroll
        for (int mt = 0; mt < 4; mt++)
            #pragma unroll
            for (int r = 0; r < 4; r++) {
                float v = acc2[mt][r] + psum[(wm * 64 + mt * 16 + q * 4 + r) * 17 + lm];
                pslab[(mt * 16 + q * 4 + r) * N_CLASSES + lm] = v;
            }
    }
}

// ---------------- reduce 32 slabs + b2 + log_softmax ----------------
__global__ __launch_bounds__(256) void reduce_softmax(const float* __restrict__ part,
                                                      const float* __restrict__ b2,
                                                      float* __restrict__ out) {
    int t = threadIdx.x;
    int row = blockIdx.x * 16 + (t >> 4);
    int cls = t & 15;
    float v = b2[cls];
    #pragma unroll
    for (int s = 0; s < 32; s++)
        v += part[((long)s * N_NODES + row) * N_CLASSES + cls];
    float mx = v;
    #pragma unroll
    for (int off = 1; off < 16; off <<= 1)
        mx = fmaxf(mx, __shfl_xor(mx, off, 64));
    float e = __expf(v - mx);
    float sm = e;
    #pragma unroll
    for (int off = 1; off < 16; off <<= 1)
        sm += __shfl_xor(sm, off, 64);
    out[(long)row * N_CLASSES + cls] = v - mx - __logf(sm);
}

// ---------------- launch ----------------

extern "C" void kernel_launch(void* const* d_in, const int* in_sizes, int n_in,
                              void* d_out, int out_size, void* d_ws, size_t ws_size,
                              hipStream_t stream) {
    const float* x  = (const float*)d_in[0];
    const int*   ei = (const int*)d_in[1];
    const float* W1 = (const float*)d_in[2];
    const float* b1 = (const float*)d_in[3];
    const float* W2 = (const float*)d_in[4];
    const float* b2 = (const float*)d_in[5];
    float* out = (float*)d_out;
    char* ws = (char*)d_ws;

    float*    part  = (float*)(ws);                          // 32*8192*16*4 = 16777216
    ushort_t* xagg  = (ushort_t*)(ws + 16777216);            // 8192*768*2   = 12582912
    ushort_t* xbf   = (ushort_t*)(ws + 29360128);            // 8192*768*2   = 12582912
    ushort_t* W1T   = (ushort_t*)(ws + 41943040);            // 4096*768*2   =  6291456
    ushort_t* W2T   = (ushort_t*)(ws + 48234496);            // 16*4096*2    =   131072
    int*      cnt   = (int*)(ws + 48365568);                 // 8192*4 (zeroed)
    int*      slots = (int*)(ws + 48398336);                 // 8192*64*4 = 2097152
    int*      flag  = (int*)(ws + 50495488);                 // 4

    hipMemsetAsync(cnt, 0, 32768, stream);
    phase1<<<1808, 256, 0, stream>>>(x, xbf, W2, W2T, ei, cnt, slots, flag);
    phase2<<<11264, 256, 0, stream>>>(W1, W1T, xbf, cnt, slots, ei, flag, xagg);
    gemm1_fused<<<(N_NODES / 128) * (HIDDEN / 128), 256, 0, stream>>>(xagg, W1T, b1, W2T, part);
    reduce_softmax<<<N_NODES / 16, 256, 0, stream>>>(part, b2, out);
}

// Round 16
// 175.688 us; speedup vs baseline: 1.6111x; 1.6111x over previous
//
#include <hip/hip_runtime.h>

#define N_NODES   8192
#define N_EDGES   65536
#define IN_DIM    768
#define HIDDEN    4096
#define N_CLASSES 16
#define SLOTS     64

typedef unsigned short ushort_t;
typedef __attribute__((ext_vector_type(8))) short bf16x8;
typedef __attribute__((ext_vector_type(4))) float f32x4;

__device__ __forceinline__ ushort_t f2bf(float f) {
    union { float f; unsigned i; } v; v.f = f;
    unsigned r = v.i + 0x7FFFu + ((v.i >> 16) & 1u);   // RNE
    return (ushort_t)(r >> 16);
}
__device__ __forceinline__ float bf2f(ushort_t u) {
    union { unsigned i; float f; } v; v.i = ((unsigned)u) << 16; return v.f;
}

// offset field intentionally NOT used: semantics unverified on gfx950 (round-10 NaN)
#define GLD_LDS16(gp, lp) \
    __builtin_amdgcn_global_load_lds((const __attribute__((address_space(1))) void*)(gp), \
                                     (__attribute__((address_space(3))) void*)(lp), 16, 0, 0)

__device__ __forceinline__ int esrc(const int* ei, int f32mode, int e) {
    return f32mode ? ei[e] : ei[2 * e];
}
__device__ __forceinline__ int edst(const int* ei, int f32mode, int e) {
    return f32mode ? ei[N_EDGES + e] : ei[2 * N_EDGES + 2 * e];
}

// ---------------- phase1: conv_w2 + conv_x + bucket ----------------
__global__ __launch_bounds__(256) void phase1(const float* __restrict__ x,
                                              ushort_t* __restrict__ xbf,
                                              const float* __restrict__ W2,
                                              ushort_t* __restrict__ W2T,
                                              const int* __restrict__ ei,
                                              int* __restrict__ cnt,
                                              int* __restrict__ slots,
                                              int* __restrict__ flag) {
    int b = blockIdx.x, t = threadIdx.x;
    if (b < 16) {
        __shared__ ushort_t ld[16 * 257];
        int k0 = b * 256;
        const float4* src = (const float4*)(W2 + (long)(k0 + t) * N_CLASSES);
        #pragma unroll
        for (int j = 0; j < 4; j++) {
            float4 v = src[j];
            ld[(j * 4 + 0) * 257 + t] = f2bf(v.x);
            ld[(j * 4 + 1) * 257 + t] = f2bf(v.y);
            ld[(j * 4 + 2) * 257 + t] = f2bf(v.z);
            ld[(j * 4 + 3) * 257 + t] = f2bf(v.w);
        }
        __syncthreads();
        #pragma unroll
        for (int c = 0; c < 16; c++)
            W2T[c * HIDDEN + k0 + t] = ld[c * 257 + t];
    } else if (b < 1552) {
        long i = (long)(b - 16) * 1024 + t;            // 1536 blocks x 4 float4/thread
        #pragma unroll
        for (int p = 0; p < 4; p++) {
            float4 v = ((const float4*)x)[i + p * 256];
            ushort4 r = { f2bf(v.x), f2bf(v.y), f2bf(v.z), f2bf(v.w) };
            ((ushort4*)xbf)[i + p * 256] = r;
        }
    } else {
        // per-block layout detect: int32 layout -> odd words are real values (nonzero
        // over 4096 samples); int64 layout -> odd words are high halves == 0.
        __shared__ int sv[256];
        int v = 0;
        for (int e = t; e < 4096; e += 256) v |= ei[2 * e + 1];
        sv[t] = v;
        __syncthreads();
        for (int off = 128; off > 0; off >>= 1) {
            if (t < off) sv[t] |= sv[t + off];
            __syncthreads();
        }
        int f = (sv[0] != 0) ? 1 : 0;
        if (b == 1552 && t == 0) *flag = f;            // for aggregate's overflow path
        int e = (b - 1552) * 256 + t;                  // 65536
        int s = esrc(ei, f, e), d = edst(ei, f, e);
        int p = atomicAdd(&cnt[d], 1);
        if (p < SLOTS) slots[d * SLOTS + p] = s;
    }
}

// ---------------- phase2: conv_w1 + aggregate ----------------
__global__ __launch_bounds__(256) void phase2(const float* __restrict__ W1,
                                              ushort_t* __restrict__ W1T,
                                              const ushort_t* __restrict__ xbf,
                                              const int* __restrict__ cnt,
                                              const int* __restrict__ slots,
                                              const int* __restrict__ ei,
                                              const int* __restrict__ flag,
                                              ushort_t* __restrict__ xagg) {
    int b = blockIdx.x, t = threadIdx.x;
    if (b < 3072) {
        __shared__ ushort_t tile[32][33];
        int n0 = (b & 127) * 32, k0 = (b >> 7) * 32;
        int tx = t & 31, ty = t >> 5;                  // ty: 0..7
        #pragma unroll
        for (int j = 0; j < 4; j++) {
            int k = ty * 4 + j;
            tile[k][tx] = f2bf(W1[(k0 + k) * HIDDEN + n0 + tx]);
        }
        __syncthreads();
        #pragma unroll
        for (int j = 0; j < 4; j++) {
            int n = ty * 4 + j;
            W1T[(n0 + n) * IN_DIM + k0 + tx] = tile[tx][n];
        }
        return;
    }
    if (t >= 192) return;                              // wave 3 idle in aggregate blocks
    int w = t >> 6, l = t & 63;
    int d = b - 3072;
    int fo = w * 256 + l * 4;                          // feature offset
    int cd = cnt[d];
    float wd = rsqrtf((float)(cd + 1));
    ushort4 sv = *(const ushort4*)(xbf + (long)d * IN_DIM + fo);
    float a0 = wd * bf2f(sv.x), a1 = wd * bf2f(sv.y);
    float a2 = wd * bf2f(sv.z), a3 = wd * bf2f(sv.w);

    if (cd <= SLOTS) {
        const int* sl = slots + d * SLOTS;
        int j = 0;
        for (; j + 4 <= cd; j += 4) {
            int s0 = sl[j], s1 = sl[j + 1], s2 = sl[j + 2], s3 = sl[j + 3];
            float w0 = rsqrtf((float)(cnt[s0] + 1));
            float w1 = rsqrtf((float)(cnt[s1] + 1));
            float w2 = rsqrtf((float)(cnt[s2] + 1));
            float w3 = rsqrtf((float)(cnt[s3] + 1));
            ushort4 v0 = *(const ushort4*)(xbf + (long)s0 * IN_DIM + fo);
            ushort4 v1 = *(const ushort4*)(xbf + (long)s1 * IN_DIM + fo);
            ushort4 v2 = *(const ushort4*)(xbf + (long)s2 * IN_DIM + fo);
            ushort4 v3 = *(const ushort4*)(xbf + (long)s3 * IN_DIM + fo);
            a0 = fmaf(w0, bf2f(v0.x), a0); a1 = fmaf(w0, bf2f(v0.y), a1);
            a2 = fmaf(w0, bf2f(v0.z), a2); a3 = fmaf(w0, bf2f(v0.w), a3);
            a0 = fmaf(w1, bf2f(v1.x), a0); a1 = fmaf(w1, bf2f(v1.y), a1);
            a2 = fmaf(w1, bf2f(v1.z), a2); a3 = fmaf(w1, bf2f(v1.w), a3);
            a0 = fmaf(w2, bf2f(v2.x), a0); a1 = fmaf(w2, bf2f(v2.y), a1);
            a2 = fmaf(w2, bf2f(v2.z), a2); a3 = fmaf(w2, bf2f(v2.w), a3);
            a0 = fmaf(w3, bf2f(v3.x), a0); a1 = fmaf(w3, bf2f(v3.y), a1);
            a2 = fmaf(w3, bf2f(v3.z), a2); a3 = fmaf(w3, bf2f(v3.w), a3);
        }
        for (; j < cd; j++) {
            int s = sl[j];
            float ws = rsqrtf((float)(cnt[s] + 1));
            ushort4 v = *(const ushort4*)(xbf + (long)s * IN_DIM + fo);
            a0 = fmaf(ws, bf2f(v.x), a0); a1 = fmaf(ws, bf2f(v.y), a1);
            a2 = fmaf(ws, bf2f(v.z), a2); a3 = fmaf(ws, bf2f(v.w), a3);
        }
    } else {
        int f = *flag;
        for (int e = 0; e < N_EDGES; e++) {
            if (edst(ei, f, e) == d) {
                int s = esrc(ei, f, e);
                float ws = rsqrtf((float)(cnt[s] + 1));
                ushort4 v = *(const ushort4*)(xbf + (long)s * IN_DIM + fo);
                a0 = fmaf(ws, bf2f(v.x), a0); a1 = fmaf(ws, bf2f(v.y), a1);
                a2 = fmaf(ws, bf2f(v.z), a2); a3 = fmaf(ws, bf2f(v.w), a3);
            }
        }
    }
    ushort4 r = { f2bf(a0 * wd), f2bf(a1 * wd), f2bf(a2 * wd), f2bf(a3 * wd) };
    *(ushort4*)(xagg + (long)d * IN_DIM + fo) = r;
}

// ---------------- fused GEMM1 + ReLU + partial GEMM2 (32 slabs) ----------------
// BK=64, persistent staging pointers. Two-pass epilogue -> LDS 32768 (5 blocks/CU if
// VGPRs allow). NO min-waves launch bound: R15's (256,5) forced VGPR=48 + acc spills.
__global__ __launch_bounds__(256) void gemm1_fused(const ushort_t* __restrict__ A,
                                                   const ushort_t* __restrict__ Bt,
                                                   const float* __restrict__ b1,
                                                   const ushort_t* __restrict__ W2T,
                                                   float* __restrict__ part) {
    __shared__ char smem[32768];
    ushort_t* ldsA = (ushort_t*)smem;              // [2][128*32] bf16 = 16 KB
    ushort_t* ldsB = (ushort_t*)(smem + 16384);    // [2][128*32] bf16 = 16 KB
    int bx = blockIdx.x & 31;          // n tile  (4096/128 = 32)
    int by = blockIdx.x >> 5;          // m tile  (8192/128 = 64)
    int m0 = by * 128, n0 = bx * 128;
    int t = threadIdx.x;
    int w = t >> 6, l = t & 63;
    int wm = w & 1, wn = w >> 1;
    int q = l >> 4, lm = l & 15;

    f32x4 acc[4][4] = {};

    // swizzled fragment-read offsets (constant across K since single-buffered)
    int offA[4], offB[4];
    #pragma unroll
    for (int mt = 0; mt < 4; mt++) {
        int m = wm * 64 + mt * 16 + lm;
        offA[mt] = m * 32 + (q ^ ((m >> 1) & 3)) * 8;
    }
    #pragma unroll
    for (int nt = 0; nt < 4; nt++) {
        int n = wn * 64 + nt * 16 + lm;
        offB[nt] = n * 32 + (q ^ ((n >> 1) & 3)) * 8;
    }

    // persistent staging pointers: [slab][i] for A and B, bumped each iteration
    const ushort_t* pA[2][2];
    const ushort_t* pB[2][2];
    #pragma unroll
    for (int i = 0; i < 2; i++) {
        int L = i * 256 + t;
        int row = L >> 2;
        int cg = (L & 3) ^ ((row >> 1) & 3);
        const ushort_t* a0 = A + (long)(m0 + row) * IN_DIM + cg * 8;
        const ushort_t* b0 = Bt + (long)(n0 + row) * IN_DIM + cg * 8;
        pA[0][i] = a0;      pA[1][i] = a0 + 32;
        pB[0][i] = b0;      pB[1][i] = b0 + 32;
    }

    for (int it = 0; it < IN_DIM / 64; it++) {     // 12 iterations
        __syncthreads();
        #pragma unroll
        for (int i = 0; i < 2; i++) {
            GLD_LDS16(pA[0][i], ldsA + (i * 256 + w * 64) * 8);
            GLD_LDS16(pB[0][i], ldsB + (i * 256 + w * 64) * 8);
            GLD_LDS16(pA[1][i], ldsA + 4096 + (i * 256 + w * 64) * 8);
            GLD_LDS16(pB[1][i], ldsB + 4096 + (i * 256 + w * 64) * 8);
        }
        #pragma unroll
        for (int i = 0; i < 2; i++) {              // bump: +64 k-positions
            pA[0][i] += 64; pA[1][i] += 64;
            pB[0][i] += 64; pB[1][i] += 64;
        }
        __syncthreads();

        #pragma unroll
        for (int j = 0; j < 2; j++) {
            bf16x8 af[4], bfr[4];
            #pragma unroll
            for (int mt = 0; mt < 4; mt++)
                af[mt] = *(const bf16x8*)(ldsA + j * 4096 + offA[mt]);
            #pragma unroll
            for (int nt = 0; nt < 4; nt++)
                bfr[nt] = *(const bf16x8*)(ldsB + j * 4096 + offB[nt]);
            #pragma unroll
            for (int mt = 0; mt < 4; mt++)
                #pragma unroll
                for (int nt = 0; nt < 4; nt++)
                    acc[mt][nt] = __builtin_amdgcn_mfma_f32_16x16x32_bf16(af[mt], bfr[nt], acc[mt][nt], 0, 0, 0);
        }
    }

    // ---- two-pass epilogue: bias+ReLU, C->A layout via 32-row LDS slab, x W2T ----
    __syncthreads();   // all waves done reading staging LDS before overwrite
    const int RP = 80;                                   // padded row (16B-aligned stride)
    ushort_t* myhl = (ushort_t*)smem + w * 32 * RP;      // per-wave 32x80 bf16 = 5 KB

    float bias[4];
    #pragma unroll
    for (int nt = 0; nt < 4; nt++) bias[nt] = b1[n0 + wn * 64 + nt * 16 + lm];

    bf16x8 bf2[2];
    #pragma unroll
    for (int kk = 0; kk < 2; kk++)
        bf2[kk] = *(const bf16x8*)(W2T + (long)lm * HIDDEN + n0 + wn * 64 + kk * 32 + q * 8);

    f32x4 acc2[4] = {};
    #pragma unroll
    for (int h = 0; h < 2; h++) {                        // mt halves {0,1}, {2,3}
        #pragma unroll
        for (int mt2 = 0; mt2 < 2; mt2++) {
            int mt = h * 2 + mt2;
            #pragma unroll
            for (int nt = 0; nt < 4; nt++) {
                #pragma unroll
                for (int r = 0; r < 4; r++) {
                    float v = acc[mt][nt][r] + bias[nt];
                    v = v > 0.0f ? v : 0.0f;
                    // C layout: local row = mt2*16 + q*4 + r, col = nt*16 + lm
                    myhl[(mt2 * 16 + q * 4 + r) * RP + nt * 16 + lm] = f2bf(v);
                }
            }
        }
        // same-wave DS ops to aliasing addresses stay ordered; no barrier needed
        #pragma unroll
        for (int kk = 0; kk < 2; kk++)
            #pragma unroll
            for (int mt2 = 0; mt2 < 2; mt2++) {
                bf16x8 a2 = *(const bf16x8*)(myhl + (mt2 * 16 + lm) * RP + kk * 32 + q * 8);
                acc2[h * 2 + mt2] = __builtin_amdgcn_mfma_f32_16x16x32_bf16(a2, bf2[kk], acc2[h * 2 + mt2], 0, 0, 0);
            }
    }

    // ---- merge wn=0/wn=1 partials through LDS (17-padded, conflict-free) ----
    float* psum = (float*)smem;                          // [2][64][17] fp32 = 8.7 KB
    __syncthreads();                                     // all myhl reads done
    if (wn == 1) {
        #pragma unroll
        for (int mt = 0; mt < 4; mt++)
            #pragma unroll
            for (int r = 0; r < 4; r++)
                psum[(wm * 64 + mt * 16 + q * 4 + r) * 17 + lm] = acc2[mt][r];
    }
    __syncthreads();
    if (wn == 0) {
        float* pslab = part + ((long)bx * N_NODES + m0 + wm * 64) * N_CLASSES;
        #pragma unroll
        for (int mt = 0; mt < 4; mt++)
            #pragma unroll
            for (int r = 0; r < 4; r++) {
                float v = acc2[mt][r] + psum[(wm * 64 + mt * 16 + q * 4 + r) * 17 + lm];
                pslab[(mt * 16 + q * 4 + r) * N_CLASSES + lm] = v;
            }
    }
}

// ---------------- reduce 32 slabs + b2 + log_softmax ----------------
__global__ __launch_bounds__(256) void reduce_softmax(const float* __restrict__ part,
                                                      const float* __restrict__ b2,
                                                      float* __restrict__ out) {
    int t = threadIdx.x;
    int row = blockIdx.x * 16 + (t >> 4);
    int cls = t & 15;
    float v = b2[cls];
    #pragma unroll
    for (int s = 0; s < 32; s++)
        v += part[((long)s * N_NODES + row) * N_CLASSES + cls];
    float mx = v;
    #pragma unroll
    for (int off = 1; off < 16; off <<= 1)
        mx = fmaxf(mx, __shfl_xor(mx, off, 64));
    float e = __expf(v - mx);
    float sm = e;
    #pragma unroll
    for (int off = 1; off < 16; off <<= 1)
        sm += __shfl_xor(sm, off, 64);
    out[(long)row * N_CLASSES + cls] = v - mx - __logf(sm);
}

// ---------------- launch ----------------

extern "C" void kernel_launch(void* const* d_in, const int* in_sizes, int n_in,
                              void* d_out, int out_size, void* d_ws, size_t ws_size,
                              hipStream_t stream) {
    const float* x  = (const float*)d_in[0];
    const int*   ei = (const int*)d_in[1];
    const float* W1 = (const float*)d_in[2];
    const float* b1 = (const float*)d_in[3];
    const float* W2 = (const float*)d_in[4];
    const float* b2 = (const float*)d_in[5];
    float* out = (float*)d_out;
    char* ws = (char*)d_ws;

    float*    part  = (float*)(ws);                          // 32*8192*16*4 = 16777216
    ushort_t* xagg  = (ushort_t*)(ws + 16777216);            // 8192*768*2   = 12582912
    ushort_t* xbf   = (ushort_t*)(ws + 29360128);            // 8192*768*2   = 12582912
    ushort_t* W1T   = (ushort_t*)(ws + 41943040);            // 4096*768*2   =  6291456
    ushort_t* W2T   = (ushort_t*)(ws + 48234496);            // 16*4096*2    =   131072
    int*      cnt   = (int*)(ws + 48365568);                 // 8192*4 (zeroed)
    int*      slots = (int*)(ws + 48398336);                 // 8192*64*4 = 2097152
    int*      flag  = (int*)(ws + 50495488);                 // 4

    hipMemsetAsync(cnt, 0, 32768, stream);
    phase1<<<1808, 256, 0, stream>>>(x, xbf, W2, W2T, ei, cnt, slots, flag);
    phase2<<<11264, 256, 0, stream>>>(W1, W1T, xbf, cnt, slots, ei, flag, xagg);
    gemm1_fused<<<(N_NODES / 128) * (HIDDEN / 128), 256, 0, stream>>>(xagg, W1T, b1, W2T, part);
    reduce_softmax<<<N_NODES / 16, 256, 0, stream>>>(part, b2, out);
}